// Round 7
// baseline (332.427 us; speedup 1.0000x reference)
//
#include <hip/hip_runtime.h>
#include <math.h>

#define S 2048
#define H 16
#define D 64
#define V 1024

typedef float f32x4 __attribute__((ext_vector_type(4)));
typedef __bf16 bf16x8 __attribute__((ext_vector_type(8)));
typedef unsigned short u16;

#define GLOBAL_AS __attribute__((address_space(1)))
#define LDS_AS __attribute__((address_space(3)))

__device__ __forceinline__ u16 f2bf(float x) {
    unsigned u = __float_as_uint(x);
    u = u + 0x7FFFu + ((u >> 16) & 1u);   // RNE
    return (u16)(u >> 16);
}
__device__ __forceinline__ float bf2f(u16 b) {
    return __uint_as_float(((unsigned)b) << 16);
}

#if __has_builtin(__builtin_amdgcn_global_load_lds)
#define HAS_ASYNC 1
#endif

// async 16B/lane global->LDS; lds base wave-uniform, HW scatters lane*16.
__device__ __forceinline__ void async_ld16(const u16* g, u16* ldsu, int lane) {
#ifdef HAS_ASYNC
    auto gp = reinterpret_cast<GLOBAL_AS void*>(reinterpret_cast<uintptr_t>(g));
    auto lp = reinterpret_cast<LDS_AS void*>(reinterpret_cast<uintptr_t>(ldsu));
    __builtin_amdgcn_global_load_lds(gp, lp, 16, 0, 0);
#else
    *(uint4*)((char*)ldsu + lane * 16) = *(const uint4*)g;
#endif
}

// ---------------- prep: f32 -> bf16, 5 arrays, float4-vectorized ------------
__global__ __launch_bounds__(256) void prep5(
    const float* __restrict__ a0, u16* __restrict__ b0, int n0,
    const float* __restrict__ a1, u16* __restrict__ b1, int n1,
    const float* __restrict__ a2, u16* __restrict__ b2, int n2,
    const float* __restrict__ a3, u16* __restrict__ b3, int n3,
    const float* __restrict__ a4, u16* __restrict__ b4, int n4)
{
    const int tot = n0 + n1 + n2 + n3 + n4;   // float4 units
    for (int i = blockIdx.x * 256 + threadIdx.x; i < tot; i += gridDim.x * 256) {
        const float* s; u16* d; int j = i;
        if (j < n0) { s = a0; d = b0; }
        else if ((j -= n0) < n1) { s = a1; d = b1; }
        else if ((j -= n1) < n2) { s = a2; d = b2; }
        else if ((j -= n2) < n3) { s = a3; d = b3; }
        else { j -= n3; s = a4; d = b4; }
        float4 f = ((const float4*)s)[j];
        ((ushort4*)d)[j] = make_ushort4(f2bf(f.x), f2bf(f.y), f2bf(f.z), f2bf(f.w));
    }
}

// ---------------- combined projection GEMM (pure bf16, m97-style) ----------
__global__ __launch_bounds__(256) void gemm_proj(
    const u16* __restrict__ x_h, const u16* __restrict__ rel_h,
    const u16* __restrict__ Wq_h, const u16* __restrict__ Wpos_h,
    u16* __restrict__ qk_h, u16* __restrict__ Vt_g, u16* __restrict__ P_h)
{
    __shared__ u16 A_s[128 * 32];
    __shared__ u16 B_s[128 * 32];

    const int bid = blockIdx.x;
    const bool g1 = bid < 384;
    const int m0 = (g1 ? (bid / 24) : ((bid - 384) / 8)) * 128;
    const int n0 = (g1 ? (bid % 24) : ((bid - 384) % 8)) * 128;
    const u16* Ag = g1 ? x_h : rel_h;
    const u16* Bg = g1 ? Wq_h : Wpos_h;

    const int tid = threadIdx.x;
    const int lane = tid & 63;
    const int w = tid >> 6;
    const int wm = (w & 1) * 64, wn = (w >> 1) * 64;
    const int fr = lane & 15;
    const int fq = lane >> 4;
    const int lr = lane >> 2, lc = (lane & 3) * 8;

    f32x4 acc[4][4] = {};

    for (int k0 = 0; k0 < 1024; k0 += 32) {
        __syncthreads();
#pragma unroll
        for (int i = 0; i < 2; ++i) {
            const int r0 = w * 32 + i * 16;
            async_ld16(Ag + (size_t)(m0 + r0 + lr) * 1024 + k0 + lc, A_s + r0 * 32, lane);
            async_ld16(Bg + (size_t)(n0 + r0 + lr) * 1024 + k0 + lc, B_s + r0 * 32, lane);
        }
        __syncthreads();

        bf16x8 a[4], b[4];
#pragma unroll
        for (int t = 0; t < 4; ++t) {
            a[t] = *(const bf16x8*)&A_s[(wm + t * 16 + fr) * 32 + fq * 8];
            b[t] = *(const bf16x8*)&B_s[(wn + t * 16 + fr) * 32 + fq * 8];
        }
#pragma unroll
        for (int mi = 0; mi < 4; ++mi)
#pragma unroll
            for (int ni = 0; ni < 4; ++ni)
                acc[mi][ni] = __builtin_amdgcn_mfma_f32_16x16x32_bf16(
                    a[mi], b[ni], acc[mi][ni], 0, 0, 0);
    }

    const int er = fq * 4;
    if (g1 && n0 >= 2048) {
#pragma unroll
        for (int mi = 0; mi < 4; ++mi)
#pragma unroll
            for (int ni = 0; ni < 4; ++ni) {
                const int col = n0 - 2048 + wn + ni * 16 + fr;
                const int mrow = m0 + wm + mi * 16 + er;
                *(ushort4*)&Vt_g[(size_t)col * 2048 + mrow] = make_ushort4(
                    f2bf(acc[mi][ni][0]), f2bf(acc[mi][ni][1]),
                    f2bf(acc[mi][ni][2]), f2bf(acc[mi][ni][3]));
            }
    } else {
        u16* Cb = g1 ? qk_h : P_h;
        const int ldc = g1 ? 2048 : 1024;
#pragma unroll
        for (int mi = 0; mi < 4; ++mi)
#pragma unroll
            for (int ni = 0; ni < 4; ++ni)
#pragma unroll
                for (int g = 0; g < 4; ++g)
                    Cb[(size_t)(m0 + wm + mi * 16 + er + g) * ldc + n0 + wn + ni * 16 + fr] =
                        f2bf(acc[mi][ni][g]);
    }
}

// ---------------- MFMA flash attention: 2-way j-split, sc aliases K -------
// grid (32, 16, 2). Block z handles j-tiles z, z+2, ... Partials are exactly
// combinable (no-max softmax): O = (O0+O1)/(l0+l1). LDS 36.9 KB -> 4 blk/CU.
__global__ __launch_bounds__(256, 4) void attn_mfma(
    const u16* __restrict__ qk_h, const u16* __restrict__ Vt_g,
    const u16* __restrict__ P_h,
    const float* __restrict__ u_vec, const float* __restrict__ v_vec,
    float* __restrict__ Op0, float* __restrict__ Op1,
    float* __restrict__ L0, float* __restrict__ L1)
{
    const int h = blockIdx.y;
    const int z = blockIdx.z;
    const int tile = ((blockIdx.y >> 3) & 1) ? blockIdx.x : (gridDim.x - 1 - blockIdx.x);
    const int i0 = tile * 64;
    const int tid = threadIdx.x;
    const int lane = tid & 63;
    const int w = tid >> 6;
    const int fr = lane & 15;
    const int fq = lane >> 4;

    __shared__ u16 K_s[64 * 72];    // B [n=j][k=d]; after QK, aliased as sc/p
    __shared__ u16 Vt_s[64 * 72];   // B [n=d][k=j]
    __shared__ u16 P_s[128 * 72];   // B [n=idx][k=d]
    u16* sc_s = K_s;                // shifted qp bf16, then p (A-layout)

    // ---- q fragments in registers ----
    bf16x8 qu[2], qv[2];
    {
        const int row = i0 + w * 16 + fr;
        const int base = h * 64 + fq * 8;
#pragma unroll
        for (int c = 0; c < 2; ++c) {
            bf16x8 q8 = *(const bf16x8*)(qk_h + (size_t)row * 2048 + base + c * 32);
            float4 u0 = *(const float4*)(u_vec + base + c * 32);
            float4 u1 = *(const float4*)(u_vec + base + c * 32 + 4);
            float4 v0 = *(const float4*)(v_vec + base + c * 32);
            float4 v1 = *(const float4*)(v_vec + base + c * 32 + 4);
            const float uf[8] = {u0.x, u0.y, u0.z, u0.w, u1.x, u1.y, u1.z, u1.w};
            const float vf[8] = {v0.x, v0.y, v0.z, v0.w, v1.x, v1.y, v1.z, v1.w};
#pragma unroll
            for (int j = 0; j < 8; ++j) {
                const float qf = (float)q8[j];
                qu[c][j] = (__bf16)(qf + uf[j]);
                qv[c][j] = (__bf16)(qf + vf[j]);
            }
        }
    }

    const int rKV = tid >> 2;
    const int cKV = (tid & 3) * 16;
    const int rP = tid >> 1;
    const int cP = (tid & 1) * 32;

    uint4 pfK0, pfK1, pfV0, pfV1, pfP0, pfP1, pfP2, pfP3;
    auto load_pf = [&](int j0) {
        const u16* kg = qk_h + (size_t)(j0 + rKV) * 2048 + 1024 + h * 64 + cKV;
        pfK0 = *(const uint4*)kg;
        pfK1 = *(const uint4*)(kg + 8);
        const u16* vg = Vt_g + (size_t)(h * 64 + rKV) * 2048 + j0 + cKV;
        pfV0 = *(const uint4*)vg;
        pfV1 = *(const uint4*)(vg + 8);
        int prow = S + j0 - i0 - 64 + rP;
        if (prow > S - 1) prow = S - 1;   // clamped rows only reach masked cells
        const u16* pg = P_h + (size_t)prow * 1024 + h * 64 + cP;
        pfP0 = *(const uint4*)pg;
        pfP1 = *(const uint4*)(pg + 8);
        pfP2 = *(const uint4*)(pg + 16);
        pfP3 = *(const uint4*)(pg + 24);
    };

    f32x4 O[4] = {};
    float l[4] = {};

    load_pf(z * 64);

    for (int j0 = z * 64; j0 <= i0; j0 += 128) {
        __syncthreads();   // (1) prior iter's PV reads (Vt_s, sc_s) done
        *(uint4*)&K_s[rKV * 72 + cKV] = pfK0;
        *(uint4*)&K_s[rKV * 72 + cKV + 8] = pfK1;
        *(uint4*)&Vt_s[rKV * 72 + cKV] = pfV0;
        *(uint4*)&Vt_s[rKV * 72 + cKV + 8] = pfV1;
        *(uint4*)&P_s[rP * 72 + cP] = pfP0;
        *(uint4*)&P_s[rP * 72 + cP + 8] = pfP1;
        *(uint4*)&P_s[rP * 72 + cP + 16] = pfP2;
        *(uint4*)&P_s[rP * 72 + cP + 24] = pfP3;
        if (j0 + 128 <= i0) load_pf(j0 + 128);
        __syncthreads();   // (2)

        // ---- QK + QP MFMA ----
        f32x4 accQK[4] = {};
        f32x4 accQP[8] = {};
#pragma unroll
        for (int c = 0; c < 2; ++c) {
            const int kk = c * 32 + fq * 8;
#pragma unroll
            for (int nt = 0; nt < 4; ++nt) {
                bf16x8 b = *(const bf16x8*)&K_s[(nt * 16 + fr) * 72 + kk];
                accQK[nt] = __builtin_amdgcn_mfma_f32_16x16x32_bf16(qu[c], b, accQK[nt], 0, 0, 0);
            }
#pragma unroll
            for (int nt = 0; nt < 8; ++nt) {
                bf16x8 b = *(const bf16x8*)&P_s[(nt * 16 + fr) * 72 + kk];
                accQP[nt] = __builtin_amdgcn_mfma_f32_16x16x32_bf16(qv[c], b, accQP[nt], 0, 0, 0);
            }
        }
        __syncthreads();   // (3a) all K_s reads done before sc alias writes

        // ---- scatter QP shifted (bf16): sc[rr][j], j = idx + rr - 63 ----
#pragma unroll
        for (int nt = 0; nt < 8; ++nt)
#pragma unroll
            for (int g = 0; g < 4; ++g) {
                const int rr = w * 16 + fq * 4 + g;
                const int j = nt * 16 + fr + rr - 63;
                if (j >= 0 && j < 64) sc_s[rr * 72 + j] = f2bf(accQP[nt][g]);
            }
        __syncthreads();   // (3b)

        // ---- scores + exp (no max-shift); gather addr == p-write addr ----
        float p[4][4];
#pragma unroll
        for (int nt = 0; nt < 4; ++nt)
#pragma unroll
            for (int g = 0; g < 4; ++g) {
                const int rr = w * 16 + fq * 4 + g;
                const int j = nt * 16 + fr;
                const float s = (accQK[nt][g] + bf2f(sc_s[rr * 72 + j])) * 0.125f;
                const float e = ((j0 + j) <= (i0 + rr)) ? __expf(s) : 0.f;
                p[nt][g] = e;
                l[g] += e;
            }
#pragma unroll
        for (int nt = 0; nt < 4; ++nt)
#pragma unroll
            for (int g = 0; g < 4; ++g)
                sc_s[(w * 16 + fq * 4 + g) * 72 + nt * 16 + fr] = f2bf(p[nt][g]);
        __syncthreads();   // (4)

        // ---- PV MFMA ----
#pragma unroll
        for (int c = 0; c < 2; ++c) {
            const int kk = c * 32 + fq * 8;
            bf16x8 a = *(const bf16x8*)&sc_s[(w * 16 + fr) * 72 + kk];
#pragma unroll
            for (int nt = 0; nt < 4; ++nt) {
                bf16x8 b = *(const bf16x8*)&Vt_s[(nt * 16 + fr) * 72 + kk];
                O[nt] = __builtin_amdgcn_mfma_f32_16x16x32_bf16(a, b, O[nt], 0, 0, 0);
            }
        }
    }

    // ---- reduce l across the 16 fr-lanes ----
#pragma unroll
    for (int g = 0; g < 4; ++g)
#pragma unroll
        for (int off = 1; off < 16; off <<= 1)
            l[g] += __shfl_xor(l[g], off, 64);

    // ---- epilogue: unnormalized f32 partials + l ----
    float* Op = z ? Op1 : Op0;
    float* Lp = z ? L1 : L0;
#pragma unroll
    for (int nt = 0; nt < 4; ++nt)
#pragma unroll
        for (int g = 0; g < 4; ++g) {
            const int rr = w * 16 + fq * 4 + g;
            Op[(size_t)(i0 + rr) * 1024 + h * 64 + nt * 16 + fr] = O[nt][g];
        }
    if (fr == 0)
#pragma unroll
        for (int g = 0; g < 4; ++g)
            Lp[h * 2048 + i0 + w * 16 + fq * 4 + g] = l[g];
}

// ---------------- final GEMM with fused combine ----------------------------
// A = (Op0+Op1)/(L0+L1) converted bf16 in staging; out = A @ Wout^T, f32.
__global__ __launch_bounds__(256) void gemm_out(
    const float* __restrict__ Op0, const float* __restrict__ Op1,
    const float* __restrict__ L0, const float* __restrict__ L1,
    const u16* __restrict__ Wout_h, float* __restrict__ C)
{
    __shared__ u16 A_s[128 * 32];
    __shared__ u16 B_s[64 * 32];

    const int tid = threadIdx.x;
    const int lane = tid & 63;
    const int w = tid >> 6;
    const int m0 = blockIdx.y * 128, n0 = blockIdx.x * 64;
    const int wm = (w & 1) * 64, wn = (w >> 1) * 32;
    const int fr = lane & 15;
    const int fq = lane >> 4;
    const int lr = lane >> 2, lc = (lane & 3) * 8;
    const int arow = tid >> 1;
    const int akc = (tid & 1) * 16;

    f32x4 acc[4][2] = {};

    for (int k0 = 0; k0 < 1024; k0 += 32) {
        __syncthreads();
        {
            const int hh = (k0 + akc) >> 6;
            const int grow = m0 + arow;
            const float linv = 1.f / (L0[hh * 2048 + grow] + L1[hh * 2048 + grow]);
            const float* p0 = Op0 + (size_t)grow * 1024 + k0 + akc;
            const float* p1 = Op1 + (size_t)grow * 1024 + k0 + akc;
            u16* dst = A_s + arow * 32 + akc;
#pragma unroll
            for (int j = 0; j < 16; j += 4) {
                float4 a = *(const float4*)(p0 + j);
                float4 b = *(const float4*)(p1 + j);
                *(ushort4*)(dst + j) = make_ushort4(
                    f2bf((a.x + b.x) * linv), f2bf((a.y + b.y) * linv),
                    f2bf((a.z + b.z) * linv), f2bf((a.w + b.w) * linv));
            }
        }
        async_ld16(Wout_h + (size_t)(n0 + w * 16 + lr) * 1024 + k0 + lc,
                   B_s + w * 16 * 32, lane);
        __syncthreads();

        bf16x8 a[4], b[2];
#pragma unroll
        for (int t = 0; t < 4; ++t)
            a[t] = *(const bf16x8*)&A_s[(wm + t * 16 + fr) * 32 + fq * 8];
#pragma unroll
        for (int t = 0; t < 2; ++t)
            b[t] = *(const bf16x8*)&B_s[(wn + t * 16 + fr) * 32 + fq * 8];
#pragma unroll
        for (int mi = 0; mi < 4; ++mi)
#pragma unroll
            for (int ni = 0; ni < 2; ++ni)
                acc[mi][ni] = __builtin_amdgcn_mfma_f32_16x16x32_bf16(
                    a[mi], b[ni], acc[mi][ni], 0, 0, 0);
    }

    const int er = fq * 4;
#pragma unroll
    for (int mi = 0; mi < 4; ++mi)
#pragma unroll
        for (int ni = 0; ni < 2; ++ni)
#pragma unroll
            for (int g = 0; g < 4; ++g)
                C[(size_t)(m0 + wm + mi * 16 + er + g) * 1024 + n0 + wn + ni * 16 + fr] =
                    acc[mi][ni][g];
}

extern "C" void kernel_launch(void* const* d_in, const int* in_sizes, int n_in,
                              void* d_out, int out_size, void* d_ws, size_t ws_size,
                              hipStream_t stream) {
    const float* x     = (const float*)d_in[0];
    const float* W_qkv = (const float*)d_in[1];
    const float* W_out = (const float*)d_in[2];
    const float* W_pos = (const float*)d_in[3];
    const float* u_vec = (const float*)d_in[4];
    const float* v_vec = (const float*)d_in[5];
    const float* rel   = (const float*)d_in[6];
    float* out = (float*)d_out;

    char* ws = (char*)d_ws;
    // staging (dead after gemm_proj; overlaid by attention partials):
    u16* x_h    = (u16*)(ws);                 // [2048][1024]  | Op0 f32 covers [0,8M)
    u16* rel_h  = (u16*)(ws + 4194304);       // [2048][1024]
    u16* Wq_h   = (u16*)(ws + 8388608);       // [3072][1024]  | Op1 f32 covers [8M,16M)
    u16* Wpos_h = (u16*)(ws + 14680064);      // [1024][1024]
    // live until the end:
    u16* Wout_h = (u16*)(ws + 16777216);      // [1024][1024]
    u16* qk_h   = (u16*)(ws + 18874368);      // [2048][2048]
    u16* Vt_g   = (u16*)(ws + 27262976);      // [1024][2048]
    u16* P_h    = (u16*)(ws + 31457280);      // [2048][1024]
    float* L0   = (float*)(ws + 35651584);    // [16][2048]
    float* L1   = (float*)(ws + 35782656);    // [16][2048]
    float* Op0  = (float*)(ws);               // [2048][1024] f32 (overlay)
    float* Op1  = (float*)(ws + 8388608);     // [2048][1024] f32 (overlay)

    prep5<<<dim3(1024), dim3(256), 0, stream>>>(
        x, x_h, 2048 * 1024 / 4,
        rel, rel_h, 2048 * 1024 / 4,
        W_qkv, Wq_h, 3072 * 1024 / 4,
        W_pos, Wpos_h, 1024 * 1024 / 4,
        W_out, Wout_h, 1024 * 1024 / 4);

    gemm_proj<<<dim3(512), dim3(256), 0, stream>>>(
        x_h, rel_h, Wq_h, Wpos_h, qk_h, Vt_g, P_h);

    attn_mfma<<<dim3(32, 16, 2), dim3(256), 0, stream>>>(
        qk_h, Vt_g, P_h, u_vec, v_vec, Op0, Op1, L0, L1);

    gemm_out<<<dim3(16, 16), dim3(256), 0, stream>>>(Op0, Op1, L0, L1, Wout_h, out);
}

// Round 8
// 246.946 us; speedup vs baseline: 1.3462x; 1.3462x over previous
//
#include <hip/hip_runtime.h>
#include <math.h>

#define S 2048
#define H 16
#define D 64
#define V 1024

typedef float f32x4 __attribute__((ext_vector_type(4)));
typedef __bf16 bf16x8 __attribute__((ext_vector_type(8)));
typedef unsigned short u16;

#define GLOBAL_AS __attribute__((address_space(1)))
#define LDS_AS __attribute__((address_space(3)))

__device__ __forceinline__ u16 f2bf(float x) {
    unsigned u = __float_as_uint(x);
    u = u + 0x7FFFu + ((u >> 16) & 1u);   // RNE
    return (u16)(u >> 16);
}
__device__ __forceinline__ float bf2f(u16 b) {
    return __uint_as_float(((unsigned)b) << 16);
}

#if __has_builtin(__builtin_amdgcn_global_load_lds)
#define HAS_ASYNC 1
#endif

// async 16B/lane global->LDS; lds base wave-uniform, HW scatters lane*16.
__device__ __forceinline__ void async_ld16(const u16* g, u16* ldsu, int lane) {
#ifdef HAS_ASYNC
    auto gp = reinterpret_cast<GLOBAL_AS void*>(reinterpret_cast<uintptr_t>(g));
    auto lp = reinterpret_cast<LDS_AS void*>(reinterpret_cast<uintptr_t>(ldsu));
    __builtin_amdgcn_global_load_lds(gp, lp, 16, 0, 0);
#else
    *(uint4*)((char*)ldsu + lane * 16) = *(const uint4*)g;
#endif
}

// ---------------- prep: f32 -> bf16, 5 arrays, float4-vectorized ------------
__global__ __launch_bounds__(256) void prep5(
    const float* __restrict__ a0, u16* __restrict__ b0, int n0,
    const float* __restrict__ a1, u16* __restrict__ b1, int n1,
    const float* __restrict__ a2, u16* __restrict__ b2, int n2,
    const float* __restrict__ a3, u16* __restrict__ b3, int n3,
    const float* __restrict__ a4, u16* __restrict__ b4, int n4)
{
    const int tot = n0 + n1 + n2 + n3 + n4;   // float4 units
    for (int i = blockIdx.x * 256 + threadIdx.x; i < tot; i += gridDim.x * 256) {
        const float* s; u16* d; int j = i;
        if (j < n0) { s = a0; d = b0; }
        else if ((j -= n0) < n1) { s = a1; d = b1; }
        else if ((j -= n1) < n2) { s = a2; d = b2; }
        else if ((j -= n2) < n3) { s = a3; d = b3; }
        else { j -= n3; s = a4; d = b4; }
        float4 f = ((const float4*)s)[j];
        ((ushort4*)d)[j] = make_ushort4(f2bf(f.x), f2bf(f.y), f2bf(f.z), f2bf(f.w));
    }
}

// ---------------- combined projection GEMM (pure bf16, m97-style) ----------
__global__ __launch_bounds__(256) void gemm_proj(
    const u16* __restrict__ x_h, const u16* __restrict__ rel_h,
    const u16* __restrict__ Wq_h, const u16* __restrict__ Wpos_h,
    u16* __restrict__ qk_h, u16* __restrict__ Vt_g, u16* __restrict__ P_h)
{
    __shared__ u16 A_s[128 * 32];
    __shared__ u16 B_s[128 * 32];

    const int bid = blockIdx.x;
    const bool g1 = bid < 384;
    const int m0 = (g1 ? (bid / 24) : ((bid - 384) / 8)) * 128;
    const int n0 = (g1 ? (bid % 24) : ((bid - 384) % 8)) * 128;
    const u16* Ag = g1 ? x_h : rel_h;
    const u16* Bg = g1 ? Wq_h : Wpos_h;

    const int tid = threadIdx.x;
    const int lane = tid & 63;
    const int w = tid >> 6;
    const int wm = (w & 1) * 64, wn = (w >> 1) * 64;
    const int fr = lane & 15;
    const int fq = lane >> 4;
    const int lr = lane >> 2, lc = (lane & 3) * 8;

    f32x4 acc[4][4] = {};

    for (int k0 = 0; k0 < 1024; k0 += 32) {
        __syncthreads();
#pragma unroll
        for (int i = 0; i < 2; ++i) {
            const int r0 = w * 32 + i * 16;
            async_ld16(Ag + (size_t)(m0 + r0 + lr) * 1024 + k0 + lc, A_s + r0 * 32, lane);
            async_ld16(Bg + (size_t)(n0 + r0 + lr) * 1024 + k0 + lc, B_s + r0 * 32, lane);
        }
        __syncthreads();

        bf16x8 a[4], b[4];
#pragma unroll
        for (int t = 0; t < 4; ++t) {
            a[t] = *(const bf16x8*)&A_s[(wm + t * 16 + fr) * 32 + fq * 8];
            b[t] = *(const bf16x8*)&B_s[(wn + t * 16 + fr) * 32 + fq * 8];
        }
#pragma unroll
        for (int mi = 0; mi < 4; ++mi)
#pragma unroll
            for (int ni = 0; ni < 4; ++ni)
                acc[mi][ni] = __builtin_amdgcn_mfma_f32_16x16x32_bf16(
                    a[mi], b[ni], acc[mi][ni], 0, 0, 0);
    }

    const int er = fq * 4;
    if (g1 && n0 >= 2048) {
#pragma unroll
        for (int mi = 0; mi < 4; ++mi)
#pragma unroll
            for (int ni = 0; ni < 4; ++ni) {
                const int col = n0 - 2048 + wn + ni * 16 + fr;
                const int mrow = m0 + wm + mi * 16 + er;
                *(ushort4*)&Vt_g[(size_t)col * 2048 + mrow] = make_ushort4(
                    f2bf(acc[mi][ni][0]), f2bf(acc[mi][ni][1]),
                    f2bf(acc[mi][ni][2]), f2bf(acc[mi][ni][3]));
            }
    } else {
        u16* Cb = g1 ? qk_h : P_h;
        const int ldc = g1 ? 2048 : 1024;
#pragma unroll
        for (int mi = 0; mi < 4; ++mi)
#pragma unroll
            for (int ni = 0; ni < 4; ++ni)
#pragma unroll
                for (int g = 0; g < 4; ++g)
                    Cb[(size_t)(m0 + wm + mi * 16 + er + g) * ldc + n0 + wn + ni * 16 + fr] =
                        f2bf(acc[mi][ni][g]);
    }
}

// ---------------- MFMA flash attention: 2 barriers/iter --------------------
// sc_s rows are WAVE-PRIVATE (scatter/gather/p-write/PV-A all touch rows
// w*16..w*16+15 only) -> no barrier in the whole softmax/PV chain. Only K/V/P
// staging is cross-wave (2 barriers). Reg prefetch of next tile overlaps
// compute. LDS 46 KB.
__global__ __launch_bounds__(256, 3) void attn_mfma(
    const u16* __restrict__ qk_h, const u16* __restrict__ Vt_g,
    const u16* __restrict__ P_h,
    const float* __restrict__ u_vec, const float* __restrict__ v_vec,
    u16* __restrict__ O_h)
{
    const int h = blockIdx.y;
    const int tile = ((blockIdx.y >> 3) & 1) ? blockIdx.x : (gridDim.x - 1 - blockIdx.x);
    const int i0 = tile * 64;
    const int tid = threadIdx.x;
    const int lane = tid & 63;
    const int w = tid >> 6;
    const int fr = lane & 15;
    const int fq = lane >> 4;

    __shared__ u16 K_s[64 * 72];    // B [n=j][k=d]
    __shared__ u16 Vt_s[64 * 72];   // B [n=d][k=j]
    __shared__ u16 P_s[128 * 72];   // B [n=idx][k=d]
    __shared__ u16 sc_s[64 * 72];   // wave-private bands: qp shifted, then p

    // ---- q fragments in registers ----
    bf16x8 qu[2], qv[2];
    {
        const int row = i0 + w * 16 + fr;
        const int base = h * 64 + fq * 8;
#pragma unroll
        for (int c = 0; c < 2; ++c) {
            bf16x8 q8 = *(const bf16x8*)(qk_h + (size_t)row * 2048 + base + c * 32);
            float4 u0 = *(const float4*)(u_vec + base + c * 32);
            float4 u1 = *(const float4*)(u_vec + base + c * 32 + 4);
            float4 v0 = *(const float4*)(v_vec + base + c * 32);
            float4 v1 = *(const float4*)(v_vec + base + c * 32 + 4);
            const float uf[8] = {u0.x, u0.y, u0.z, u0.w, u1.x, u1.y, u1.z, u1.w};
            const float vf[8] = {v0.x, v0.y, v0.z, v0.w, v1.x, v1.y, v1.z, v1.w};
#pragma unroll
            for (int j = 0; j < 8; ++j) {
                const float qf = (float)q8[j];
                qu[c][j] = (__bf16)(qf + uf[j]);
                qv[c][j] = (__bf16)(qf + vf[j]);
            }
        }
    }

    const int rKV = tid >> 2;
    const int cKV = (tid & 3) * 16;
    const int rP = tid >> 1;
    const int cP = (tid & 1) * 32;

    uint4 pfK0, pfK1, pfV0, pfV1, pfP0, pfP1, pfP2, pfP3;
    auto load_pf = [&](int j0) {
        const u16* kg = qk_h + (size_t)(j0 + rKV) * 2048 + 1024 + h * 64 + cKV;
        pfK0 = *(const uint4*)kg;
        pfK1 = *(const uint4*)(kg + 8);
        const u16* vg = Vt_g + (size_t)(h * 64 + rKV) * 2048 + j0 + cKV;
        pfV0 = *(const uint4*)vg;
        pfV1 = *(const uint4*)(vg + 8);
        int prow = S + j0 - i0 - 64 + rP;
        if (prow > S - 1) prow = S - 1;   // clamped rows only reach masked cells
        const u16* pg = P_h + (size_t)prow * 1024 + h * 64 + cP;
        pfP0 = *(const uint4*)pg;
        pfP1 = *(const uint4*)(pg + 8);
        pfP2 = *(const uint4*)(pg + 16);
        pfP3 = *(const uint4*)(pg + 24);
    };

    f32x4 O[4] = {};
    float l[4] = {};

    load_pf(0);

    for (int j0 = 0; j0 <= i0; j0 += 64) {
        __syncthreads();   // (1) prior iter's cross-wave LDS reads done
        *(uint4*)&K_s[rKV * 72 + cKV] = pfK0;
        *(uint4*)&K_s[rKV * 72 + cKV + 8] = pfK1;
        *(uint4*)&Vt_s[rKV * 72 + cKV] = pfV0;
        *(uint4*)&Vt_s[rKV * 72 + cKV + 8] = pfV1;
        *(uint4*)&P_s[rP * 72 + cP] = pfP0;
        *(uint4*)&P_s[rP * 72 + cP + 8] = pfP1;
        *(uint4*)&P_s[rP * 72 + cP + 16] = pfP2;
        *(uint4*)&P_s[rP * 72 + cP + 24] = pfP3;
        if (j0 + 64 <= i0) load_pf(j0 + 64);   // prefetch next tile
        __syncthreads();   // (2) staging visible to all waves

        // ---- QK + QP MFMA ----
        f32x4 accQK[4] = {};
        f32x4 accQP[8] = {};
#pragma unroll
        for (int c = 0; c < 2; ++c) {
            const int kk = c * 32 + fq * 8;
#pragma unroll
            for (int nt = 0; nt < 4; ++nt) {
                bf16x8 b = *(const bf16x8*)&K_s[(nt * 16 + fr) * 72 + kk];
                accQK[nt] = __builtin_amdgcn_mfma_f32_16x16x32_bf16(qu[c], b, accQK[nt], 0, 0, 0);
            }
#pragma unroll
            for (int nt = 0; nt < 8; ++nt) {
                bf16x8 b = *(const bf16x8*)&P_s[(nt * 16 + fr) * 72 + kk];
                accQP[nt] = __builtin_amdgcn_mfma_f32_16x16x32_bf16(qv[c], b, accQP[nt], 0, 0, 0);
            }
        }

        // ---- scatter QP shifted (wave-private rows): sc[rr][j], j=idx+rr-63 ----
#pragma unroll
        for (int nt = 0; nt < 8; ++nt)
#pragma unroll
            for (int g = 0; g < 4; ++g) {
                const int rr = w * 16 + fq * 4 + g;
                const int j = nt * 16 + fr + rr - 63;
                if (j >= 0 && j < 64) sc_s[rr * 72 + j] = f2bf(accQP[nt][g]);
            }
        // no barrier: gather below reads the same wave's band only

        // ---- scores + exp (no max-shift) ----
        float p[4][4];
#pragma unroll
        for (int nt = 0; nt < 4; ++nt)
#pragma unroll
            for (int g = 0; g < 4; ++g) {
                const int rr = w * 16 + fq * 4 + g;
                const int j = nt * 16 + fr;
                const float s = (accQK[nt][g] + bf2f(sc_s[rr * 72 + j])) * 0.125f;
                const float e = ((j0 + j) <= (i0 + rr)) ? __expf(s) : 0.f;
                p[nt][g] = e;
                l[g] += e;
            }
#pragma unroll
        for (int nt = 0; nt < 4; ++nt)
#pragma unroll
            for (int g = 0; g < 4; ++g)
                sc_s[(w * 16 + fq * 4 + g) * 72 + nt * 16 + fr] = f2bf(p[nt][g]);
        // no barrier: PV A-read below stays in the wave's band

        // ---- PV MFMA ----
#pragma unroll
        for (int c = 0; c < 2; ++c) {
            const int kk = c * 32 + fq * 8;
            bf16x8 a = *(const bf16x8*)&sc_s[(w * 16 + fr) * 72 + kk];
#pragma unroll
            for (int nt = 0; nt < 4; ++nt) {
                bf16x8 b = *(const bf16x8*)&Vt_s[(nt * 16 + fr) * 72 + kk];
                O[nt] = __builtin_amdgcn_mfma_f32_16x16x32_bf16(a, b, O[nt], 0, 0, 0);
            }
        }
    }

    // ---- reduce l across the 16 fr-lanes (once) ----
#pragma unroll
    for (int g = 0; g < 4; ++g)
#pragma unroll
        for (int off = 1; off < 16; off <<= 1)
            l[g] += __shfl_xor(l[g], off, 64);

    // ---- epilogue: bf16 out ----
#pragma unroll
    for (int nt = 0; nt < 4; ++nt)
#pragma unroll
        for (int g = 0; g < 4; ++g) {
            const int rr = w * 16 + fq * 4 + g;
            O_h[(size_t)(i0 + rr) * 1024 + h * 64 + nt * 16 + fr] = f2bf(O[nt][g] / l[g]);
        }
}

// ---------------- final GEMM: out = O @ Wout^T, f32 out, 128x64 tiles ------
__global__ __launch_bounds__(256) void gemm_out(
    const u16* __restrict__ O_g, const u16* __restrict__ Wout_h,
    float* __restrict__ C)
{
    __shared__ u16 A_s[128 * 32];
    __shared__ u16 B_s[64 * 32];

    const int tid = threadIdx.x;
    const int lane = tid & 63;
    const int w = tid >> 6;
    const int m0 = blockIdx.y * 128, n0 = blockIdx.x * 64;
    const int wm = (w & 1) * 64, wn = (w >> 1) * 32;
    const int fr = lane & 15;
    const int fq = lane >> 4;
    const int lr = lane >> 2, lc = (lane & 3) * 8;

    f32x4 acc[4][2] = {};

    for (int k0 = 0; k0 < 1024; k0 += 32) {
        __syncthreads();
#pragma unroll
        for (int i = 0; i < 2; ++i) {
            const int r0 = w * 32 + i * 16;
            async_ld16(O_g + (size_t)(m0 + r0 + lr) * 1024 + k0 + lc, A_s + r0 * 32, lane);
        }
        async_ld16(Wout_h + (size_t)(n0 + w * 16 + lr) * 1024 + k0 + lc,
                   B_s + w * 16 * 32, lane);
        __syncthreads();

        bf16x8 a[4], b[2];
#pragma unroll
        for (int t = 0; t < 4; ++t)
            a[t] = *(const bf16x8*)&A_s[(wm + t * 16 + fr) * 32 + fq * 8];
#pragma unroll
        for (int t = 0; t < 2; ++t)
            b[t] = *(const bf16x8*)&B_s[(wn + t * 16 + fr) * 32 + fq * 8];
#pragma unroll
        for (int mi = 0; mi < 4; ++mi)
#pragma unroll
            for (int ni = 0; ni < 2; ++ni)
                acc[mi][ni] = __builtin_amdgcn_mfma_f32_16x16x32_bf16(
                    a[mi], b[ni], acc[mi][ni], 0, 0, 0);
    }

    const int er = fq * 4;
#pragma unroll
    for (int mi = 0; mi < 4; ++mi)
#pragma unroll
        for (int ni = 0; ni < 2; ++ni)
#pragma unroll
            for (int g = 0; g < 4; ++g)
                C[(size_t)(m0 + wm + mi * 16 + er + g) * 1024 + n0 + wn + ni * 16 + fr] =
                    acc[mi][ni][g];
}

extern "C" void kernel_launch(void* const* d_in, const int* in_sizes, int n_in,
                              void* d_out, int out_size, void* d_ws, size_t ws_size,
                              hipStream_t stream) {
    const float* x     = (const float*)d_in[0];
    const float* W_qkv = (const float*)d_in[1];
    const float* W_out = (const float*)d_in[2];
    const float* W_pos = (const float*)d_in[3];
    const float* u_vec = (const float*)d_in[4];
    const float* v_vec = (const float*)d_in[5];
    const float* rel   = (const float*)d_in[6];
    float* out = (float*)d_out;

    char* ws = (char*)d_ws;
    u16* x_h    = (u16*)(ws);                 // [2048][1024]
    u16* rel_h  = (u16*)(ws + 4194304);       // [2048][1024]
    u16* Wq_h   = (u16*)(ws + 8388608);       // [3072][1024]
    u16* Wpos_h = (u16*)(ws + 14680064);      // [1024][1024]
    u16* Wout_h = (u16*)(ws + 16777216);      // [1024][1024]
    u16* qk_h   = (u16*)(ws + 18874368);      // [2048][2048] (q | k)
    u16* Vt_g   = (u16*)(ws + 27262976);      // [1024][2048]
    u16* P_h    = (u16*)(ws + 31457280);      // [2048][1024]
    u16* O_h    = (u16*)(ws + 35651584);      // [2048][1024]

    prep5<<<dim3(2048), dim3(256), 0, stream>>>(
        x, x_h, 2048 * 1024 / 4,
        rel, rel_h, 2048 * 1024 / 4,
        W_qkv, Wq_h, 3072 * 1024 / 4,
        W_pos, Wpos_h, 1024 * 1024 / 4,
        W_out, Wout_h, 1024 * 1024 / 4);

    gemm_proj<<<dim3(512), dim3(256), 0, stream>>>(
        x_h, rel_h, Wq_h, Wpos_h, qk_h, Vt_g, P_h);

    attn_mfma<<<dim3(32, 16), dim3(256), 0, stream>>>(
        qk_h, Vt_g, P_h, u_vec, v_vec, O_h);

    gemm_out<<<dim3(16, 16), dim3(256), 0, stream>>>(O_h, Wout_h, out);
}

// Round 9
// 196.240 us; speedup vs baseline: 1.6940x; 1.2584x over previous
//
#include <hip/hip_runtime.h>
#include <math.h>

#define S 2048
#define H 16
#define D 64
#define V 1024

typedef float f32x4 __attribute__((ext_vector_type(4)));
typedef __bf16 bf16x8 __attribute__((ext_vector_type(8)));
typedef unsigned short u16;

#define GLOBAL_AS __attribute__((address_space(1)))
#define LDS_AS __attribute__((address_space(3)))

__device__ __forceinline__ u16 f2bf(float x) {
    unsigned u = __float_as_uint(x);
    u = u + 0x7FFFu + ((u >> 16) & 1u);   // RNE
    return (u16)(u >> 16);
}
__device__ __forceinline__ float bf2f(u16 b) {
    return __uint_as_float(((unsigned)b) << 16);
}

#if __has_builtin(__builtin_amdgcn_global_load_lds)
#define HAS_ASYNC 1
#endif

// async 16B/lane global->LDS; lds base wave-uniform, HW scatters lane*16.
__device__ __forceinline__ void async_ld16(const u16* g, u16* ldsu, int lane) {
#ifdef HAS_ASYNC
    auto gp = reinterpret_cast<GLOBAL_AS void*>(reinterpret_cast<uintptr_t>(g));
    auto lp = reinterpret_cast<LDS_AS void*>(reinterpret_cast<uintptr_t>(ldsu));
    __builtin_amdgcn_global_load_lds(gp, lp, 16, 0, 0);
#else
    *(uint4*)((char*)ldsu + lane * 16) = *(const uint4*)g;
#endif
}

// ---------------- prep: f32 -> bf16, 5 arrays, float4-vectorized ------------
__global__ __launch_bounds__(256) void prep5(
    const float* __restrict__ a0, u16* __restrict__ b0, int n0,
    const float* __restrict__ a1, u16* __restrict__ b1, int n1,
    const float* __restrict__ a2, u16* __restrict__ b2, int n2,
    const float* __restrict__ a3, u16* __restrict__ b3, int n3,
    const float* __restrict__ a4, u16* __restrict__ b4, int n4)
{
    const int tot = n0 + n1 + n2 + n3 + n4;   // float4 units
    for (int i = blockIdx.x * 256 + threadIdx.x; i < tot; i += gridDim.x * 256) {
        const float* s; u16* d; int j = i;
        if (j < n0) { s = a0; d = b0; }
        else if ((j -= n0) < n1) { s = a1; d = b1; }
        else if ((j -= n1) < n2) { s = a2; d = b2; }
        else if ((j -= n2) < n3) { s = a3; d = b3; }
        else { j -= n3; s = a4; d = b4; }
        float4 f = ((const float4*)s)[j];
        ((ushort4*)d)[j] = make_ushort4(f2bf(f.x), f2bf(f.y), f2bf(f.z), f2bf(f.w));
    }
}

// ---------------- combined projection GEMM (pure bf16, m97-style) ----------
__global__ __launch_bounds__(256) void gemm_proj(
    const u16* __restrict__ x_h, const u16* __restrict__ rel_h,
    const u16* __restrict__ Wq_h, const u16* __restrict__ Wpos_h,
    u16* __restrict__ qk_h, u16* __restrict__ Vt_g, u16* __restrict__ P_h)
{
    __shared__ u16 A_s[128 * 32];
    __shared__ u16 B_s[128 * 32];

    const int bid = blockIdx.x;
    const bool g1 = bid < 384;
    const int m0 = (g1 ? (bid / 24) : ((bid - 384) / 8)) * 128;
    const int n0 = (g1 ? (bid % 24) : ((bid - 384) % 8)) * 128;
    const u16* Ag = g1 ? x_h : rel_h;
    const u16* Bg = g1 ? Wq_h : Wpos_h;

    const int tid = threadIdx.x;
    const int lane = tid & 63;
    const int w = tid >> 6;
    const int wm = (w & 1) * 64, wn = (w >> 1) * 64;
    const int fr = lane & 15;
    const int fq = lane >> 4;
    const int lr = lane >> 2, lc = (lane & 3) * 8;

    f32x4 acc[4][4] = {};

    for (int k0 = 0; k0 < 1024; k0 += 32) {
        __syncthreads();
#pragma unroll
        for (int i = 0; i < 2; ++i) {
            const int r0 = w * 32 + i * 16;
            async_ld16(Ag + (size_t)(m0 + r0 + lr) * 1024 + k0 + lc, A_s + r0 * 32, lane);
            async_ld16(Bg + (size_t)(n0 + r0 + lr) * 1024 + k0 + lc, B_s + r0 * 32, lane);
        }
        __syncthreads();

        bf16x8 a[4], b[4];
#pragma unroll
        for (int t = 0; t < 4; ++t) {
            a[t] = *(const bf16x8*)&A_s[(wm + t * 16 + fr) * 32 + fq * 8];
            b[t] = *(const bf16x8*)&B_s[(wn + t * 16 + fr) * 32 + fq * 8];
        }
#pragma unroll
        for (int mi = 0; mi < 4; ++mi)
#pragma unroll
            for (int ni = 0; ni < 4; ++ni)
                acc[mi][ni] = __builtin_amdgcn_mfma_f32_16x16x32_bf16(
                    a[mi], b[ni], acc[mi][ni], 0, 0, 0);
    }

    const int er = fq * 4;
    if (g1 && n0 >= 2048) {
#pragma unroll
        for (int mi = 0; mi < 4; ++mi)
#pragma unroll
            for (int ni = 0; ni < 4; ++ni) {
                const int col = n0 - 2048 + wn + ni * 16 + fr;
                const int mrow = m0 + wm + mi * 16 + er;
                *(ushort4*)&Vt_g[(size_t)col * 2048 + mrow] = make_ushort4(
                    f2bf(acc[mi][ni][0]), f2bf(acc[mi][ni][1]),
                    f2bf(acc[mi][ni][2]), f2bf(acc[mi][ni][3]));
            }
    } else {
        u16* Cb = g1 ? qk_h : P_h;
        const int ldc = g1 ? 2048 : 1024;
#pragma unroll
        for (int mi = 0; mi < 4; ++mi)
#pragma unroll
            for (int ni = 0; ni < 4; ++ni)
#pragma unroll
                for (int g = 0; g < 4; ++g)
                    Cb[(size_t)(m0 + wm + mi * 16 + er + g) * ldc + n0 + wn + ni * 16 + fr] =
                        f2bf(acc[mi][ni][g]);
    }
}

// ---------------- MFMA flash attention: shuffle-based shift-gather ---------
// Shift identity: score row rr = w*16+fq*4+g needs QP col idx = j + (63-rr),
// and 63-rr = 16*(3-w) + (15-4*fq-g): tile offset a=3-w is WAVE-UNIFORM, so
// wave w computes only QP tiles [3-w, 8-w) (5 of 8) and the shifted value is
// an in-wave shuffle: lane (fq<<4)|((fr+b)&15), register g, tile +1 on wrap.
// No LDS scatter/gather. p round-trips LDS (C->A layout) in wave-private rows.
__global__ __launch_bounds__(256, 3) void attn_mfma(
    const u16* __restrict__ qk_h, const u16* __restrict__ Vt_g,
    const u16* __restrict__ P_h,
    const float* __restrict__ u_vec, const float* __restrict__ v_vec,
    u16* __restrict__ O_h)
{
    const int h = blockIdx.y;
    const int tile = ((blockIdx.y >> 3) & 1) ? blockIdx.x : (gridDim.x - 1 - blockIdx.x);
    const int i0 = tile * 64;
    const int tid = threadIdx.x;
    const int lane = tid & 63;
    const int w = tid >> 6;
    const int fr = lane & 15;
    const int fq = lane >> 4;

    __shared__ u16 K_s[64 * 72];    // B [n=j][k=d]
    __shared__ u16 Vt_s[64 * 72];   // B [n=d][k=j]
    __shared__ u16 P_s[128 * 72];   // B [n=idx][k=d]
    __shared__ u16 p_s[64 * 72];    // p, wave-private row bands

    // ---- q fragments in registers ----
    bf16x8 qu[2], qv[2];
    {
        const int row = i0 + w * 16 + fr;
        const int base = h * 64 + fq * 8;
#pragma unroll
        for (int c = 0; c < 2; ++c) {
            bf16x8 q8 = *(const bf16x8*)(qk_h + (size_t)row * 2048 + base + c * 32);
            float4 u0 = *(const float4*)(u_vec + base + c * 32);
            float4 u1 = *(const float4*)(u_vec + base + c * 32 + 4);
            float4 v0 = *(const float4*)(v_vec + base + c * 32);
            float4 v1 = *(const float4*)(v_vec + base + c * 32 + 4);
            const float uf[8] = {u0.x, u0.y, u0.z, u0.w, u1.x, u1.y, u1.z, u1.w};
            const float vf[8] = {v0.x, v0.y, v0.z, v0.w, v1.x, v1.y, v1.z, v1.w};
#pragma unroll
            for (int j = 0; j < 8; ++j) {
                const float qf = (float)q8[j];
                qu[c][j] = (__bf16)(qf + uf[j]);
                qv[c][j] = (__bf16)(qf + vf[j]);
            }
        }
    }

    const int rKV = tid >> 2;
    const int cKV = (tid & 3) * 16;
    const int rP = tid >> 1;
    const int cP = (tid & 1) * 32;

    uint4 pfK0, pfK1, pfV0, pfV1, pfP0, pfP1, pfP2, pfP3;
    auto load_pf = [&](int j0) {
        const u16* kg = qk_h + (size_t)(j0 + rKV) * 2048 + 1024 + h * 64 + cKV;
        pfK0 = *(const uint4*)kg;
        pfK1 = *(const uint4*)(kg + 8);
        const u16* vg = Vt_g + (size_t)(h * 64 + rKV) * 2048 + j0 + cKV;
        pfV0 = *(const uint4*)vg;
        pfV1 = *(const uint4*)(vg + 8);
        int prow = S + j0 - i0 - 64 + rP;
        if (prow > S - 1) prow = S - 1;   // clamped rows only reach masked cells
        const u16* pg = P_h + (size_t)prow * 1024 + h * 64 + cP;
        pfP0 = *(const uint4*)pg;
        pfP1 = *(const uint4*)(pg + 8);
        pfP2 = *(const uint4*)(pg + 16);
        pfP3 = *(const uint4*)(pg + 24);
    };

    f32x4 O[4] = {};
    float l[4] = {};

    const int tbase = 3 - w;          // wave-uniform QP tile offset
    const int bsh = 15 - fq * 4;      // b for g=0; b_g = bsh - g

    load_pf(0);

    for (int j0 = 0; j0 <= i0; j0 += 64) {
        __syncthreads();   // (1) prior iter's cross-wave LDS reads done
        *(uint4*)&K_s[rKV * 72 + cKV] = pfK0;
        *(uint4*)&K_s[rKV * 72 + cKV + 8] = pfK1;
        *(uint4*)&Vt_s[rKV * 72 + cKV] = pfV0;
        *(uint4*)&Vt_s[rKV * 72 + cKV + 8] = pfV1;
        *(uint4*)&P_s[rP * 72 + cP] = pfP0;
        *(uint4*)&P_s[rP * 72 + cP + 8] = pfP1;
        *(uint4*)&P_s[rP * 72 + cP + 16] = pfP2;
        *(uint4*)&P_s[rP * 72 + cP + 24] = pfP3;
        if (j0 + 64 <= i0) load_pf(j0 + 64);   // prefetch next tile
        __syncthreads();   // (2) staging visible to all waves

        // ---- QK (4 tiles) + QP (5 tiles, wave-specific window) MFMA ----
        f32x4 accQK[4] = {};
        f32x4 accQP[5] = {};
#pragma unroll
        for (int c = 0; c < 2; ++c) {
            const int kk = c * 32 + fq * 8;
#pragma unroll
            for (int nt = 0; nt < 4; ++nt) {
                bf16x8 b = *(const bf16x8*)&K_s[(nt * 16 + fr) * 72 + kk];
                accQK[nt] = __builtin_amdgcn_mfma_f32_16x16x32_bf16(qu[c], b, accQK[nt], 0, 0, 0);
            }
#pragma unroll
            for (int t = 0; t < 5; ++t) {
                bf16x8 b = *(const bf16x8*)&P_s[((tbase + t) * 16 + fr) * 72 + kk];
                accQP[t] = __builtin_amdgcn_mfma_f32_16x16x32_bf16(qv[c], b, accQP[t], 0, 0, 0);
            }
        }

        // ---- shuffle-shift + scores + exp (no max-shift) ----
        float p[4][4];
#pragma unroll
        for (int nt = 0; nt < 4; ++nt)
#pragma unroll
            for (int g = 0; g < 4; ++g) {
                const int b = bsh - g;                 // in [0,15]
                const int srcfr = fr + b;              // in [0,30]
                const int srcLane = (fq << 4) | (srcfr & 15);
                const float lo = __shfl(accQP[nt][g], srcLane, 64);
                const float hi = __shfl(accQP[nt + 1][g], srcLane, 64);
                const float qp = (srcfr < 16) ? lo : hi;
                const int rr = w * 16 + fq * 4 + g;
                const int j = nt * 16 + fr;
                const float s = (accQK[nt][g] + qp) * 0.125f;
                const float e = ((j0 + j) <= (i0 + rr)) ? __expf(s) : 0.f;
                p[nt][g] = e;
                l[g] += e;
            }
#pragma unroll
        for (int nt = 0; nt < 4; ++nt)
#pragma unroll
            for (int g = 0; g < 4; ++g)
                p_s[(w * 16 + fq * 4 + g) * 72 + nt * 16 + fr] = f2bf(p[nt][g]);
        // no barrier: PV A-read below stays in the wave's band

        // ---- PV MFMA ----
#pragma unroll
        for (int c = 0; c < 2; ++c) {
            const int kk = c * 32 + fq * 8;
            bf16x8 a = *(const bf16x8*)&p_s[(w * 16 + fr) * 72 + kk];
#pragma unroll
            for (int nt = 0; nt < 4; ++nt) {
                bf16x8 b = *(const bf16x8*)&Vt_s[(nt * 16 + fr) * 72 + kk];
                O[nt] = __builtin_amdgcn_mfma_f32_16x16x32_bf16(a, b, O[nt], 0, 0, 0);
            }
        }
    }

    // ---- reduce l across the 16 fr-lanes (once) ----
#pragma unroll
    for (int g = 0; g < 4; ++g)
#pragma unroll
        for (int off = 1; off < 16; off <<= 1)
            l[g] += __shfl_xor(l[g], off, 64);

    // ---- epilogue: bf16 out ----
#pragma unroll
    for (int nt = 0; nt < 4; ++nt)
#pragma unroll
        for (int g = 0; g < 4; ++g) {
            const int rr = w * 16 + fq * 4 + g;
            O_h[(size_t)(i0 + rr) * 1024 + h * 64 + nt * 16 + fr] = f2bf(O[nt][g] / l[g]);
        }
}

// ---------------- final GEMM: out = O @ Wout^T, f32 out, 128x64 tiles ------
__global__ __launch_bounds__(256) void gemm_out(
    const u16* __restrict__ O_g, const u16* __restrict__ Wout_h,
    float* __restrict__ C)
{
    __shared__ u16 A_s[128 * 32];
    __shared__ u16 B_s[64 * 32];

    const int tid = threadIdx.x;
    const int lane = tid & 63;
    const int w = tid >> 6;
    const int m0 = blockIdx.y * 128, n0 = blockIdx.x * 64;
    const int wm = (w & 1) * 64, wn = (w >> 1) * 32;
    const int fr = lane & 15;
    const int fq = lane >> 4;
    const int lr = lane >> 2, lc = (lane & 3) * 8;

    f32x4 acc[4][2] = {};

    for (int k0 = 0; k0 < 1024; k0 += 32) {
        __syncthreads();
#pragma unroll
        for (int i = 0; i < 2; ++i) {
            const int r0 = w * 32 + i * 16;
            async_ld16(O_g + (size_t)(m0 + r0 + lr) * 1024 + k0 + lc, A_s + r0 * 32, lane);
        }
        async_ld16(Wout_h + (size_t)(n0 + w * 16 + lr) * 1024 + k0 + lc,
                   B_s + w * 16 * 32, lane);
        __syncthreads();

        bf16x8 a[4], b[2];
#pragma unroll
        for (int t = 0; t < 4; ++t)
            a[t] = *(const bf16x8*)&A_s[(wm + t * 16 + fr) * 32 + fq * 8];
#pragma unroll
        for (int t = 0; t < 2; ++t)
            b[t] = *(const bf16x8*)&B_s[(wn + t * 16 + fr) * 32 + fq * 8];
#pragma unroll
        for (int mi = 0; mi < 4; ++mi)
#pragma unroll
            for (int ni = 0; ni < 2; ++ni)
                acc[mi][ni] = __builtin_amdgcn_mfma_f32_16x16x32_bf16(
                    a[mi], b[ni], acc[mi][ni], 0, 0, 0);
    }

    const int er = fq * 4;
#pragma unroll
    for (int mi = 0; mi < 4; ++mi)
#pragma unroll
        for (int ni = 0; ni < 2; ++ni)
#pragma unroll
            for (int g = 0; g < 4; ++g)
                C[(size_t)(m0 + wm + mi * 16 + er + g) * 1024 + n0 + wn + ni * 16 + fr] =
                    acc[mi][ni][g];
}

extern "C" void kernel_launch(void* const* d_in, const int* in_sizes, int n_in,
                              void* d_out, int out_size, void* d_ws, size_t ws_size,
                              hipStream_t stream) {
    const float* x     = (const float*)d_in[0];
    const float* W_qkv = (const float*)d_in[1];
    const float* W_out = (const float*)d_in[2];
    const float* W_pos = (const float*)d_in[3];
    const float* u_vec = (const float*)d_in[4];
    const float* v_vec = (const float*)d_in[5];
    const float* rel   = (const float*)d_in[6];
    float* out = (float*)d_out;

    char* ws = (char*)d_ws;
    u16* x_h    = (u16*)(ws);                 // [2048][1024]
    u16* rel_h  = (u16*)(ws + 4194304);       // [2048][1024]
    u16* Wq_h   = (u16*)(ws + 8388608);       // [3072][1024]
    u16* Wpos_h = (u16*)(ws + 14680064);      // [1024][1024]
    u16* Wout_h = (u16*)(ws + 16777216);      // [1024][1024]
    u16* qk_h   = (u16*)(ws + 18874368);      // [2048][2048] (q | k)
    u16* Vt_g   = (u16*)(ws + 27262976);      // [1024][2048]
    u16* P_h    = (u16*)(ws + 31457280);      // [2048][1024]
    u16* O_h    = (u16*)(ws + 35651584);      // [2048][1024]

    prep5<<<dim3(2048), dim3(256), 0, stream>>>(
        x, x_h, 2048 * 1024 / 4,
        rel, rel_h, 2048 * 1024 / 4,
        W_qkv, Wq_h, 3072 * 1024 / 4,
        W_pos, Wpos_h, 1024 * 1024 / 4,
        W_out, Wout_h, 1024 * 1024 / 4);

    gemm_proj<<<dim3(512), dim3(256), 0, stream>>>(
        x_h, rel_h, Wq_h, Wpos_h, qk_h, Vt_g, P_h);

    attn_mfma<<<dim3(32, 16), dim3(256), 0, stream>>>(
        qk_h, Vt_g, P_h, u_vec, v_vec, O_h);

    gemm_out<<<dim3(16, 16), dim3(256), 0, stream>>>(O_h, Wout_h, out);
}